// Round 6
// baseline (466.906 us; speedup 1.0000x reference)
//
#include <hip/hip_runtime.h>
#include <math.h>

// ---------------------------------------------------------------------------
// R6: convs 2-5 single-K-slab implicit-GEMM MFMA with fused BN stats AND
// (conv2/conv3) fused 2x2 maxpool in the epilogue: store pooled raw max+min
// planes (exact for either sign of the BN scale; f16 rounding point identical
// to the unfused path). conv2 reshaped to 16x16 tile, COT=4/PT=4 (4:1
// MFMA:ds_read). f16 in/out, fp32 accum.
// MFMA 16x16x32 f16: A m=lane&15,k=quad*8+j; B n=lane&15,k=quad*8+j;
//                    D col(n)=lane&15, row(m)=quad*4+reg.
// ---------------------------------------------------------------------------

#define PI2F 6.283185307179586f

typedef _Float16 half8 __attribute__((ext_vector_type(8)));
typedef _Float16 half4v __attribute__((ext_vector_type(4)));
typedef float f32x4 __attribute__((ext_vector_type(4)));

// ---------------- FFT branch ------------------------------------------------

__device__ __forceinline__ int bitrev8(int x) {
  x = ((x & 0x0F) << 4) | ((x >> 4) & 0x0F);
  x = ((x & 0x33) << 2) | ((x >> 2) & 0x33);
  x = ((x & 0x55) << 1) | ((x >> 1) & 0x55);
  return x;
}

__global__ __launch_bounds__(64)
void fft_rows(const float* __restrict__ x, float2* __restrict__ out) {
  __shared__ float2 s[256];
  __shared__ float2 tw[128];
  int blk = blockIdx.x;
  const float* rowp = x + (size_t)blk * 256;
  int t = threadIdx.x;
  for (int i = t; i < 128; i += 64) {
    float sn, cs;
    sincosf(-(PI2F / 256.f) * (float)i, &sn, &cs);
    tw[i] = make_float2(cs, sn);
  }
  #pragma unroll
  for (int e = 0; e < 4; ++e) {
    int i = t + (e << 6);
    s[bitrev8(i)] = make_float2(rowp[i], 0.f);
  }
  __syncthreads();
  #pragma unroll
  for (int st = 1; st <= 8; ++st) {
    int half = 1 << (st - 1);
    #pragma unroll
    for (int j = 0; j < 2; ++j) {
      int bf = t + (j << 6);
      int pos = bf & (half - 1);
      int grp = bf >> (st - 1);
      int i0 = (grp << st) | pos;
      int i1 = i0 + half;
      int k = pos << (8 - st);
      float cs = tw[k].x, sn = tw[k].y;
      float2 a = s[i0], b = s[i1];
      float tr = cs * b.x - sn * b.y;
      float ti = cs * b.y + sn * b.x;
      s[i0] = make_float2(a.x + tr, a.y + ti);
      s[i1] = make_float2(a.x - tr, a.y - ti);
    }
    __syncthreads();
  }
  float2* op = out + (size_t)blk * 256;
  #pragma unroll
  for (int e = 0; e < 4; ++e) { int i = t + (e << 6); op[i] = s[i]; }
}

__device__ __forceinline__ int radial_bin(int r2) {
  int j = (int)(sqrtf((float)r2) * 0.25f);
  while ((j + 1) * (j + 1) * 16 <= r2) ++j;
  while (j > 0 && j * j * 16 > r2) --j;
  return j;
}

__global__ __launch_bounds__(256)
void fft_cols_radial_v2(const float2* __restrict__ f, float* __restrict__ radial) {
  __shared__ float2 s[8][258];
  __shared__ float2 tw[128];
  __shared__ float bins[8][32];
  int b = blockIdx.x >> 5;
  int col0 = (blockIdx.x & 31) * 8;
  int t = threadIdx.x;
  for (int i = t; i < 128; i += 256) {
    float sn, cs;
    sincosf(-(PI2F / 256.f) * (float)i, &sn, &cs);
    tw[i] = make_float2(cs, sn);
  }
  ((float*)bins)[t] = 0.f;
  for (int idx = t; idx < 2048; idx += 256) {
    int row = idx >> 3, c = idx & 7;
    s[c][bitrev8(row)] = f[(size_t)b * 65536 + row * 256 + col0 + c];
  }
  __syncthreads();
  int c = t >> 5, l = t & 31;
  float2* sc = &s[c][0];
  #pragma unroll
  for (int st = 1; st <= 8; ++st) {
    int half = 1 << (st - 1);
    #pragma unroll
    for (int j = 0; j < 4; ++j) {
      int bf = l + (j << 5);
      int pos = bf & (half - 1);
      int grp = bf >> (st - 1);
      int i0 = (grp << st) | pos;
      int i1 = i0 + half;
      int k = pos << (8 - st);
      float cs = tw[k].x, sn = tw[k].y;
      float2 a = sc[i0], bb = sc[i1];
      float tr = cs * bb.x - sn * bb.y;
      float ti = cs * bb.y + sn * bb.x;
      sc[i0] = make_float2(a.x + tr, a.y + ti);
      sc[i1] = make_float2(a.x - tr, a.y - ti);
    }
    __syncthreads();
  }
  int dx = col0 + c - 128;
  #pragma unroll
  for (int e = 0; e < 8; ++e) {
    int i = l * 8 + e;
    float2 v = sc[i];
    float ps = v.x * v.x + v.y * v.y;
    int dy = i - 128;
    int r2 = dx * dx + dy * dy;
    if (r2 < 16384) atomicAdd(&bins[c][radial_bin(r2)], ps);
  }
  __syncthreads();
  if (t < 32) {
    float s0 = bins[0][t] + bins[1][t] + bins[2][t] + bins[3][t] +
               bins[4][t] + bins[5][t] + bins[6][t] + bins[7][t];
    atomicAdd(&radial[b * 32 + t], s0);
  }
}

__device__ __forceinline__ int isqrt_(int v) {
  int r = (int)sqrtf((float)v);
  while (r * r > v) --r;
  while ((r + 1) * (r + 1) <= v) ++r;
  return r;
}

__global__ __launch_bounds__(256)
void radial_finalize_v3(const float* __restrict__ radial, float* __restrict__ pf0) {
  __shared__ int red[4];
  __shared__ int cnt_s;
  int j = blockIdx.x, t = threadIdx.x;
  int dy = t - 128;
  int lo = 16 * j * j, hi = 16 * (j + 1) * (j + 1);
  int d2 = dy * dy;
  int cnt = 0;
  int tHi = hi - 1 - d2;
  if (tHi >= 0) {
    int rHi = isqrt_(tHi);
    int nHi = min(rHi, 127) + min(rHi, 128) + 1;
    int nLo = 0;
    int tLo = lo - 1 - d2;
    if (tLo >= 0) { int rLo = isqrt_(tLo); nLo = min(rLo, 127) + min(rLo, 128) + 1; }
    cnt = nHi - nLo;
  }
  #pragma unroll
  for (int off = 32; off > 0; off >>= 1) cnt += __shfl_down(cnt, off);
  if ((t & 63) == 0) red[t >> 6] = cnt;
  __syncthreads();
  if (t == 0) cnt_s = red[0] + red[1] + red[2] + red[3];
  __syncthreads();
  if (t < 16) {
    float cf = (float)cnt_s;
    float sum = radial[t * 32 + j];
    float val = cf > 0.f ? sum / fmaxf(cf, 1.f) : 0.f;
    pf0[t * 32 + j] = logf(val + 1e-10f);
  }
}

// ---------------- weight transforms -----------------------------------------

__global__ __launch_bounds__(256)
void wtrans_all(const float* __restrict__ cw2, const float* __restrict__ cw3,
                const float* __restrict__ cw4, const float* __restrict__ pcw,
                _Float16* __restrict__ wb2, _Float16* __restrict__ wb3,
                _Float16* __restrict__ wb4, _Float16* __restrict__ wbp) {
  int blk = blockIdx.x;
  const float* src; _Float16* dst; int COUT, CIN, KK, i;
  if (blk < 200)       { src = cw2; dst = wb2; COUT = 64;  CIN = 32;  KK = 25; i = blk * 256; }
  else if (blk < 488)  { src = cw3; dst = wb3; COUT = 128; CIN = 64;  KK = 9;  i = (blk - 200) * 256; }
  else if (blk < 1640) { src = cw4; dst = wb4; COUT = 256; CIN = 128; KK = 9;  i = (blk - 488) * 256; }
  else                 { src = pcw; dst = wbp; COUT = 128; CIN = 256; KK = 9;  i = (blk - 1640) * 256; }
  i += threadIdx.x;
  if (i >= COUT * CIN * KK) return;
  int ci = i % CIN;
  int r = i / CIN;
  int co = r % COUT;
  int tap = r / COUT;
  dst[i] = (_Float16)src[((size_t)co * CIN + ci) * KK + tap];
}

// ---------------- conv1 (Cin=1, 5x5): float4 register-window ----------------

__device__ __forceinline__ void load16(float* d, const float* p) {
  f32x4 v0 = *(const f32x4*)(p);
  f32x4 v1 = *(const f32x4*)(p + 4);
  f32x4 v2 = *(const f32x4*)(p + 8);
  f32x4 v3 = *(const f32x4*)(p + 12);
  #pragma unroll
  for (int e = 0; e < 4; ++e) { d[e] = v0[e]; d[4+e] = v1[e]; d[8+e] = v2[e]; d[12+e] = v3[e]; }
}

__global__ __launch_bounds__(256)
void conv1_stats_v3(const float* __restrict__ x, const float* __restrict__ w,
                    float* __restrict__ stats) {
  __shared__ float lds[12 * 264];
  __shared__ float r1[4][32], r2[4][32];
  int t = threadIdx.x;
  int y0 = blockIdx.x * 8, n = blockIdx.y;
  const float* xp = x + (size_t)n * 65536;
  for (int i = t; i < 12 * 264; i += 256) {
    int r = i / 264, cc = i % 264;
    int gy = y0 + r - 2, gx = cc - 4;
    lds[i] = (gy >= 0 && gy < 256 && gx >= 0 && gx < 256) ? xp[gy * 256 + gx] : 0.f;
  }
  __syncthreads();
  int c = t & 31, xg = t >> 5;
  float wreg[25];
  #pragma unroll
  for (int k = 0; k < 25; ++k) wreg[k] = w[c * 25 + k];
  float s1 = 0.f, s2 = 0.f;
  for (int strip = 0; strip < 4; ++strip) {
    int px0 = xg * 8 + strip * 64;
    float f[5][16];
    #pragma unroll
    for (int rr = 0; rr < 4; ++rr) load16(f[rr], &lds[rr * 264 + px0]);
    #pragma unroll
    for (int r = 0; r < 8; ++r) {
      load16(f[(r + 4) % 5], &lds[(r + 4) * 264 + px0]);
      f32x4 A = {0.f, 0.f, 0.f, 0.f}, B = {0.f, 0.f, 0.f, 0.f};
      #pragma unroll
      for (int ky = 0; ky < 5; ++ky) {
        const float* fr = f[(r + ky) % 5];
        #pragma unroll
        for (int kx = 0; kx < 5; ++kx) {
          float wv = wreg[ky * 5 + kx];
          f32x4 ia = {fr[2 + kx], fr[3 + kx], fr[4 + kx], fr[5 + kx]};
          f32x4 ib = {fr[6 + kx], fr[7 + kx], fr[8 + kx], fr[9 + kx]};
          A += wv * ia; B += wv * ib;
        }
      }
      s1 += A[0] + A[1] + A[2] + A[3] + B[0] + B[1] + B[2] + B[3];
      s2 += A[0]*A[0] + A[1]*A[1] + A[2]*A[2] + A[3]*A[3]
          + B[0]*B[0] + B[1]*B[1] + B[2]*B[2] + B[3]*B[3];
    }
  }
  s1 += __shfl_down(s1, 32);
  s2 += __shfl_down(s2, 32);
  if ((t & 63) < 32) { r1[t >> 6][t & 31] = s1; r2[t >> 6][t & 31] = s2; }
  __syncthreads();
  if (t < 32) {
    atomicAdd(&stats[t],      r1[0][t] + r1[1][t] + r1[2][t] + r1[3][t]);
    atomicAdd(&stats[32 + t], r2[0][t] + r2[1][t] + r2[2][t] + r2[3][t]);
  }
}

__global__ __launch_bounds__(256)
void conv1_apply_v3(const float* __restrict__ x, const float* __restrict__ w,
                    const float* __restrict__ stats, const float* __restrict__ g,
                    const float* __restrict__ bb, _Float16* __restrict__ pool1) {
  __shared__ float lds[6 * 264];
  int t = threadIdx.x;
  int py = blockIdx.x, n = blockIdx.y;
  const float* xp = x + (size_t)n * 65536;
  for (int i = t; i < 6 * 264; i += 256) {
    int r = i / 264, cc = i % 264;
    int gy = 2 * py + r - 2, gx = cc - 4;
    lds[i] = (gy >= 0 && gy < 256 && gx >= 0 && gx < 256) ? xp[gy * 256 + gx] : 0.f;
  }
  __syncthreads();
  int c = t & 31, xg = t >> 5;
  float wreg[25];
  #pragma unroll
  for (int k = 0; k < 25; ++k) wreg[k] = w[c * 25 + k];
  float mean = stats[c] * (1.f / 1048576.f);
  float var  = stats[32 + c] * (1.f / 1048576.f) - mean * mean;
  float sc = g[c] / sqrtf(var + 1e-5f);
  float sh = bb[c] - mean * sc;
  for (int iter = 0; iter < 4; ++iter) {
    int p0 = xg * 4 + iter * 32;
    float f[6][16];
    #pragma unroll
    for (int rr = 0; rr < 6; ++rr) load16(f[rr], &lds[rr * 264 + 2 * p0]);
    f32x4 acc[2][2];
    #pragma unroll
    for (int sy = 0; sy < 2; ++sy)
      #pragma unroll
      for (int h = 0; h < 2; ++h) acc[sy][h] = (f32x4){0.f, 0.f, 0.f, 0.f};
    #pragma unroll
    for (int sy = 0; sy < 2; ++sy)
      #pragma unroll
      for (int ky = 0; ky < 5; ++ky) {
        const float* fr = f[sy + ky];
        #pragma unroll
        for (int kx = 0; kx < 5; ++kx) {
          float wv = wreg[ky * 5 + kx];
          f32x4 ia = {fr[2 + kx], fr[3 + kx], fr[4 + kx], fr[5 + kx]};
          f32x4 ib = {fr[6 + kx], fr[7 + kx], fr[8 + kx], fr[9 + kx]};
          acc[sy][0] += wv * ia; acc[sy][1] += wv * ib;
        }
      }
    #pragma unroll
    for (int pp = 0; pp < 4; ++pp) {
      float v00 = acc[0][(2*pp) >> 2][(2*pp) & 3];
      float v01 = acc[0][(2*pp+1) >> 2][(2*pp+1) & 3];
      float v10 = acc[1][(2*pp) >> 2][(2*pp) & 3];
      float v11 = acc[1][(2*pp+1) >> 2][(2*pp+1) & 3];
      float m = fmaxf(fmaxf(v00, v01), fmaxf(v10, v11));
      pool1[(((size_t)n * 128 + py) * 128 + p0 + pp) * 32 + c] =
          (_Float16)fmaxf(m * sc + sh, 0.f);
    }
  }
}

// ---------------- single-K-slab implicit-GEMM MFMA conv ---------------------
// CW co-waves x (4/CW) pos-waves. POOL=1: epilogue stores 2x2-pooled raw
// max+min planes (minoff = plane offset in elements); POOL=0: full-res raw.
// BN stats from full-res fp32 accs either way; 8 atomic slices.

template <int CIN, int COUT, int H, int W, int K, int TH, int TW, int CW,
          int COT, int PT, int SLAB, int POOL>
__global__ __launch_bounds__(256)
void conv_mfma3(const _Float16* __restrict__ in, const _Float16* __restrict__ wb,
                _Float16* __restrict__ out, float* __restrict__ stats,
                size_t minoff) {
  constexpr int P = K / 2, R = TH + 2 * P, XW = TW + 2 * P, PIX = R * XW;
  constexpr int TAPS = K * K, CSP = SLAB + 8;
  constexpr int NCC = SLAB / 32, NPH = CIN / SLAB, SUBS = SLAB / 8;
  constexpr int PW = 4 / CW, COB = CW * 16 * COT;
  static_assert(TH * TW == PW * 16 * PT, "pos tile mismatch");
  static_assert(TW == 16, "row-per-fragment requires TW=16");
  static_assert(!POOL || (PT % 2 == 0), "pool needs even PT");
  __shared__ _Float16 lds[PIX * CSP];
  __shared__ float sst[2][COB];
  int t = threadIdx.x;
  int lane = t & 63, wv = t >> 6;
  int lane15 = lane & 15, quad = lane >> 4;
  constexpr int WT = W / TW;
  int x0 = (blockIdx.x % WT) * TW, y0 = (blockIdx.x / WT) * TH;
  int coB = blockIdx.y * COB;
  int nb = blockIdx.z;
  int co_off = (wv % CW) * (16 * COT);
  int rowbase = (wv / CW) * PT;

  for (int i = t; i < 2 * COB; i += 256) ((float*)sst)[i] = 0.f;

  f32x4 acc[COT][PT];
  #pragma unroll
  for (int ct = 0; ct < COT; ++ct)
    #pragma unroll
    for (int pt = 0; pt < PT; ++pt)
      #pragma unroll
      for (int e = 0; e < 4; ++e) acc[ct][pt][e] = 0.f;

  int bbase[PT];
  #pragma unroll
  for (int pt = 0; pt < PT; ++pt)
    bbase[pt] = ((rowbase + pt) * XW + lane15) * CSP + quad * 8;
  const _Float16* aptr[COT];
  #pragma unroll
  for (int ct = 0; ct < COT; ++ct)
    aptr[ct] = wb + (size_t)(coB + co_off + ct * 16 + lane15) * CIN + quad * 8;

  const _Float16* inb = in + (size_t)nb * H * W * CIN;

  #pragma unroll
  for (int ph = 0; ph < NPH; ++ph) {
    constexpr int ITEMS = PIX * SUBS;
    for (int i = t; i < ITEMS; i += 256) {
      int sub = i % SUBS, pix = i / SUBS;
      int r = pix / XW, xx = pix % XW;
      int gy = y0 + r - P, gx = x0 + xx - P;
      half8 v;
      #pragma unroll
      for (int j = 0; j < 8; ++j) v[j] = (_Float16)0.f;
      if (gy >= 0 && gy < H && gx >= 0 && gx < W)
        v = *(const half8*)(inb + ((size_t)gy * W + gx) * CIN + ph * SLAB + sub * 8);
      *(half8*)(&lds[pix * CSP + sub * 8]) = v;
    }
    __syncthreads();
    #pragma unroll
    for (int cc = 0; cc < NCC; ++cc) {
      #pragma unroll
      for (int tap = 0; tap < TAPS; ++tap) {
        int ky = tap / K, kx = tap % K;
        half8 a[COT], b[PT];
        #pragma unroll
        for (int ct = 0; ct < COT; ++ct)
          a[ct] = *(const half8*)(aptr[ct] + (size_t)tap * COUT * CIN +
                                  ph * SLAB + cc * 32);
        #pragma unroll
        for (int pt = 0; pt < PT; ++pt)
          b[pt] = *(const half8*)(&lds[bbase[pt] + (ky * XW + kx) * CSP + cc * 32]);
        #pragma unroll
        for (int ct = 0; ct < COT; ++ct)
          #pragma unroll
          for (int pt = 0; pt < PT; ++pt)
            acc[ct][pt] = __builtin_amdgcn_mfma_f32_16x16x32_f16(
                a[ct], b[pt], acc[ct][pt], 0, 0, 0);
      }
    }
    if (ph + 1 < NPH) __syncthreads();
  }

  if (POOL) {
    #pragma unroll
    for (int ct = 0; ct < COT; ++ct)
      #pragma unroll
      for (int pp = 0; pp < PT; pp += 2) {
        half4v hmax, hmin;
        #pragma unroll
        for (int e = 0; e < 4; ++e) {
          float vmx = fmaxf(acc[ct][pp][e], acc[ct][pp + 1][e]);
          float vmn = fminf(acc[ct][pp][e], acc[ct][pp + 1][e]);
          float omx = fmaxf(vmx, __shfl_xor(vmx, 1));
          float omn = fminf(vmn, __shfl_xor(vmn, 1));
          hmax[e] = (_Float16)omx; hmin[e] = (_Float16)omn;
        }
        if ((lane15 & 1) == 0) {
          int co = coB + co_off + ct * 16 + quad * 4;
          int prow = (y0 + rowbase + pp) >> 1;
          int pcol = (x0 >> 1) + (lane15 >> 1);
          size_t idx = (((size_t)nb * (H / 2) + prow) * (W / 2) + pcol) * COUT + co;
          *(half4v*)(out + idx) = hmax;
          *(half4v*)(out + minoff + idx) = hmin;
        }
      }
  } else {
    #pragma unroll
    for (int ct = 0; ct < COT; ++ct)
      #pragma unroll
      for (int pt = 0; pt < PT; ++pt) {
        int co = coB + co_off + ct * 16 + quad * 4;
        int y = y0 + rowbase + pt, x = x0 + lane15;
        _Float16* op = out + (((size_t)nb * H + y) * W + x) * COUT + co;
        half4v h;
        #pragma unroll
        for (int e = 0; e < 4; ++e) h[e] = (_Float16)acc[ct][pt][e];
        *(half4v*)op = h;
      }
  }

  #pragma unroll
  for (int ct = 0; ct < COT; ++ct)
    #pragma unroll
    for (int e = 0; e < 4; ++e) {
      float sv = 0.f, sq = 0.f;
      #pragma unroll
      for (int pt = 0; pt < PT; ++pt) {
        float v = acc[ct][pt][e];
        sv += v; sq += v * v;
      }
      sv += __shfl_xor(sv, 1); sq += __shfl_xor(sq, 1);
      sv += __shfl_xor(sv, 2); sq += __shfl_xor(sq, 2);
      sv += __shfl_xor(sv, 4); sq += __shfl_xor(sq, 4);
      sv += __shfl_xor(sv, 8); sq += __shfl_xor(sq, 8);
      if (lane15 == 0) {
        int cl = co_off + ct * 16 + quad * 4 + e;
        atomicAdd(&sst[0][cl], sv);
        atomicAdd(&sst[1][cl], sq);
      }
    }
  __syncthreads();
  float* st = stats + (blockIdx.x & 7) * 2 * COUT;
  for (int i = t; i < COB; i += 256) {
    atomicAdd(&st[coB + i], sst[0][i]);
    atomicAdd(&st[COUT + coB + i], sst[1][i]);
  }
}

// ---------------- BN epilogues (sum 8 stat slices) --------------------------

__device__ __forceinline__ void bn_coeff(const float* stats, int C, int c,
                                         float invN, const float* g,
                                         const float* bb, float* sc, float* sh) {
  float s1 = 0.f, s2 = 0.f;
  #pragma unroll
  for (int s = 0; s < 8; ++s) {
    s1 += stats[s * 2 * C + c];
    s2 += stats[s * 2 * C + C + c];
  }
  float mean = s1 * invN;
  float var  = s2 * invN - mean * mean;
  float k = g[c] / sqrtf(var + 1e-5f);
  *sc = k; *sh = bb[c] - mean * k;
}

// pooled-raw (max/min planes) -> BN+ReLU applied pooled activations
__global__ __launch_bounds__(256)
void bn_relu_sel(const _Float16* __restrict__ raw, const float* __restrict__ stats,
                 const float* __restrict__ g, const float* __restrict__ bb,
                 _Float16* __restrict__ out, int C, int total, float invN,
                 size_t minoff) {
  __shared__ float scs[256], shs[256];
  int t = threadIdx.x, n = blockIdx.y;
  for (int c = t; c < C; c += 256) bn_coeff(stats, C, c, invN, g, bb, &scs[c], &shs[c]);
  __syncthreads();
  for (int i = blockIdx.x * 256 + t; i < total; i += gridDim.x * 256) {
    int c = i % C;
    size_t idx = (size_t)n * total + i;
    float sc = scs[c];
    float v = sc >= 0.f ? (float)raw[idx] : (float)raw[minoff + idx];
    out[idx] = (_Float16)fmaxf(sc * v + shs[c], 0.f);
  }
}

__global__ __launch_bounds__(256)
void bn_relu_h16(const _Float16* __restrict__ x, const float* __restrict__ stats,
                 const float* __restrict__ g, const float* __restrict__ bb,
                 _Float16* __restrict__ out, int C, int HW, float invN) {
  __shared__ float scs[256], shs[256];
  int t = threadIdx.x;
  int n = blockIdx.y;
  for (int c = t; c < C; c += 256) bn_coeff(stats, C, c, invN, g, bb, &scs[c], &shs[c]);
  __syncthreads();
  int total = HW * C;
  int chunk = total / gridDim.x;
  int base = blockIdx.x * chunk;
  const _Float16* xp = x + (size_t)n * total;
  _Float16* op = out + (size_t)n * total;
  for (int i = base + t; i < base + chunk; i += 256) {
    int c = i % C;
    op[i] = (_Float16)fmaxf((float)xp[i] * scs[c] + shs[c], 0.f);
  }
}

__global__ __launch_bounds__(256)
void bn_avgpool_concat(const _Float16* __restrict__ x, const float* __restrict__ stats,
                       const float* __restrict__ g, const float* __restrict__ bb,
                       float* __restrict__ concat, float invN) {
  __shared__ float scs[128], shs[128];
  int t = threadIdx.x;
  int n = blockIdx.x;
  for (int c = t; c < 128; c += 256) bn_coeff(stats, 128, c, invN, g, bb, &scs[c], &shs[c]);
  __syncthreads();
  for (int i = t; i < 2048; i += 256) {
    int c = i & 127, opix = i >> 7;
    int py = opix >> 2, px = opix & 3;
    float sc = scs[c], sh = shs[c];
    float s = 0.f;
    for (int yy = 0; yy < 8; ++yy)
      for (int xx = 0; xx < 8; ++xx)
        s += fmaxf((float)x[(((size_t)n * 32 + py * 8 + yy) * 32 + px * 8 + xx) * 128 + c] * sc + sh, 0.f);
    concat[(size_t)n * 2112 + c * 16 + opix] = s * (1.f / 64.f);
  }
}

// ---------------- MLP heads -------------------------------------------------

__global__ __launch_bounds__(64)
void linear_k(const float* __restrict__ in, const float* __restrict__ w,
              const float* __restrict__ bias, float* __restrict__ out,
              int I, int in_stride, int out_stride, int relu) {
  int o = blockIdx.x, b = blockIdx.y;
  int lane = threadIdx.x;
  const float* ip = in + (size_t)b * in_stride;
  const float* wp = w + (size_t)o * I;
  float acc = 0.f;
  for (int i = lane; i < I; i += 64) acc += ip[i] * wp[i];
  #pragma unroll
  for (int off = 32; off > 0; off >>= 1) acc += __shfl_down(acc, off);
  if (lane == 0) {
    float v = acc + bias[o];
    if (relu) v = fmaxf(v, 0.f);
    out[(size_t)b * out_stride + o] = v;
  }
}

__global__ __launch_bounds__(256)
void pf_mlp(const float* __restrict__ pf0,
            const float* __restrict__ pw1, const float* __restrict__ pb1,
            const float* __restrict__ pw2, const float* __restrict__ pb2,
            const float* __restrict__ pw3, const float* __restrict__ pb3,
            float* __restrict__ concat) {
  __shared__ float a0[32], a1[256], a2[128];
  int b = blockIdx.x, t = threadIdx.x;
  if (t < 32) a0[t] = pf0[b * 32 + t];
  __syncthreads();
  {
    float s = pb1[t];
    for (int i = 0; i < 32; ++i) s += pw1[t * 32 + i] * a0[i];
    a1[t] = fmaxf(s, 0.f);
  }
  __syncthreads();
  if (t < 128) {
    float s = pb2[t];
    for (int i = 0; i < 256; ++i) s += pw2[t * 256 + i] * a1[i];
    a2[t] = fmaxf(s, 0.f);
  }
  __syncthreads();
  if (t < 64) {
    float s = pb3[t];
    for (int i = 0; i < 128; ++i) s += pw3[t * 128 + i] * a2[i];
    concat[(size_t)b * 2112 + 2048 + t] = fmaxf(s, 0.f);
  }
}

__global__ __launch_bounds__(256)
void fc_tail(const float* __restrict__ fc1o,
             const float* __restrict__ fw2, const float* __restrict__ fb2,
             const float* __restrict__ fw3, const float* __restrict__ fb3,
             const float* __restrict__ fw4, const float* __restrict__ fb4,
             float* __restrict__ out) {
  __shared__ float a1[512], a2[256], a3[128];
  int b = blockIdx.x, t = threadIdx.x;
  a1[t] = fc1o[b * 512 + t];
  a1[t + 256] = fc1o[b * 512 + t + 256];
  __syncthreads();
  {
    float s = fb2[t];
    for (int i = 0; i < 512; ++i) s += fw2[t * 512 + i] * a1[i];
    a2[t] = fmaxf(s, 0.f);
  }
  __syncthreads();
  if (t < 128) {
    float s = fb3[t];
    for (int i = 0; i < 256; ++i) s += fw3[t * 256 + i] * a2[i];
    a3[t] = fmaxf(s, 0.f);
  }
  __syncthreads();
  if (t < 2) {
    float s = fb4[t];
    for (int i = 0; i < 128; ++i) s += fw4[t * 128 + i] * a3[i];
    out[b * 2 + t] = s;
  }
}

// ---------------------------------------------------------------------------

extern "C" void kernel_launch(void* const* d_in, const int* in_sizes, int n_in,
                              void* d_out, int out_size, void* d_ws, size_t ws_size,
                              hipStream_t stream) {
  (void)in_sizes; (void)n_in; (void)out_size; (void)ws_size;
  const float* x   = (const float*)d_in[0];
  const float* cw1 = (const float*)d_in[1];
  const float* g1  = (const float*)d_in[3];
  const float* bb1 = (const float*)d_in[4];
  const float* cw2 = (const float*)d_in[5];
  const float* g2  = (const float*)d_in[7];
  const float* bb2 = (const float*)d_in[8];
  const float* cw3 = (const float*)d_in[9];
  const float* g3  = (const float*)d_in[11];
  const float* bb3 = (const float*)d_in[12];
  const float* cw4 = (const float*)d_in[13];
  const float* g4  = (const float*)d_in[15];
  const float* bb4 = (const float*)d_in[16];
  const float* pcw = (const float*)d_in[17];
  const float* pg  = (const float*)d_in[19];
  const float* pbb = (const float*)d_in[20];
  const float* pw1 = (const float*)d_in[21];
  const float* pb1 = (const float*)d_in[22];
  const float* pw2 = (const float*)d_in[23];
  const float* pb2 = (const float*)d_in[24];
  const float* pw3 = (const float*)d_in[25];
  const float* pb3 = (const float*)d_in[26];
  const float* fw1 = (const float*)d_in[27];
  const float* fb1 = (const float*)d_in[28];
  const float* fw2 = (const float*)d_in[29];
  const float* fb2 = (const float*)d_in[30];
  const float* fw3 = (const float*)d_in[31];
  const float* fb3 = (const float*)d_in[32];
  const float* fw4 = (const float*)d_in[33];
  const float* fb4 = (const float*)d_in[34];

  char* base = (char*)d_ws;
  // Region A (16.8 MB), time-multiplexed:
  //   fftbuf(8.4) -> pool2raw(max 8.4 | min 8.4) -> pool3raw(max 4.2|min 4.2)
  //   -> conv4raw(8.4) + pconvo(4.2 @ +8.4)
  float2*    fftbuf   = (float2*)(base + 0);
  _Float16*  pool2raw = (_Float16*)(base + 0);          // 2x [16,64,64,64]
  _Float16*  pool3raw = (_Float16*)(base + 0);          // 2x [16,32,32,128]
  _Float16*  conv4raw = (_Float16*)(base + 0);          // [16,32,32,256]
  _Float16*  pconvo   = (_Float16*)(base + 8388608);    // [16,32,32,128]
  _Float16*  pool1    = (_Float16*)(base + 16777216);   // [16,128,128,32]
  _Float16*  pool2    = (_Float16*)(base + 33554432);   // [16,64,64,64]
  _Float16*  pool3    = (_Float16*)(base + 41943040);   // [16,32,32,128]
  _Float16*  act4     = (_Float16*)(base + 46137344);   // [16,32,32,256]
  _Float16*  wb2      = (_Float16*)(base + 54525952);
  _Float16*  wb3      = (_Float16*)(base + 54628352);
  _Float16*  wb4      = (_Float16*)(base + 54775808);
  _Float16*  wbp      = (_Float16*)(base + 55365632);
  float*     zbase    = (float*)(base + 55955456);      // 9792 floats
  float*     stats1   = zbase;               // 64
  float*     stats2   = zbase + 64;          // 8*128
  float*     stats3   = zbase + 1088;        // 8*256
  float*     stats4   = zbase + 3136;        // 8*512
  float*     stats5   = zbase + 7232;        // 8*256
  float*     radial   = zbase + 9280;        // 512
  float*     pf0      = (float*)(base + 55994624);
  float*     concat   = (float*)(base + 55996672);      // 16*2112
  float*     fc1o     = (float*)(base + 56131840);

  hipMemsetAsync(zbase, 0, 9792 * sizeof(float), stream);

  wtrans_all<<<2792, 256, 0, stream>>>(cw2, cw3, cw4, pcw, wb2, wb3, wb4, wbp);

  // ---- FFT / power-features branch (fftbuf aliases region A) ----
  fft_rows<<<4096, 64, 0, stream>>>(x, fftbuf);
  fft_cols_radial_v2<<<512, 256, 0, stream>>>(fftbuf, radial);
  radial_finalize_v3<<<32, 256, 0, stream>>>(radial, pf0);
  pf_mlp<<<16, 256, 0, stream>>>(pf0, pw1, pb1, pw2, pb2, pw3, pb3, concat);

  // ---- conv1 ----
  conv1_stats_v3<<<dim3(32, 16), 256, 0, stream>>>(x, cw1, stats1);
  conv1_apply_v3<<<dim3(128, 16), 256, 0, stream>>>(x, cw1, stats1, g1, bb1, pool1);

  // ---- conv2: 16x16 tile, COT=4/PT=4 (CW=1), fused pool (LDS 32KB) ----
  conv_mfma3<32, 64, 128, 128, 5, 16, 16, 1, 4, 4, 32, 1>
      <<<dim3(64, 1, 16), 256, 0, stream>>>(pool1, wb2, pool2raw, stats2, 4194304);
  bn_relu_sel<<<dim3(64, 16), 256, 0, stream>>>(
      pool2raw, stats2, g2, bb2, pool2, 64, 262144, 1.f / 262144.f, 4194304);

  // ---- conv3: 8x16 tile, CW=2 COT=4/PT=4, fused pool (LDS 25.9KB) ----
  conv_mfma3<64, 128, 64, 64, 3, 8, 16, 2, 4, 4, 64, 1>
      <<<dim3(32, 1, 16), 256, 0, stream>>>(pool2, wb3, pool3raw, stats3, 2097152);
  bn_relu_sel<<<dim3(32, 16), 256, 0, stream>>>(
      pool3raw, stats3, g3, bb3, pool3, 128, 131072, 1.f / 65536.f, 2097152);

  // ---- conv4: 4x16 tile, CW=2 COT=4/PT=2, no pool (LDS 29.4KB) ----
  conv_mfma3<128, 256, 32, 32, 3, 4, 16, 2, 4, 2, 128, 0>
      <<<dim3(16, 2, 16), 256, 0, stream>>>(pool3, wb4, conv4raw, stats4, 0);
  bn_relu_h16<<<dim3(8, 16), 256, 0, stream>>>(
      conv4raw, stats4, g4, bb4, act4, 256, 1024, 1.f / 16384.f);

  // ---- pconv: 4x16 tile, CW=2 COT=2/PT=2, 2 slabs, no pool ----
  conv_mfma3<256, 128, 32, 32, 3, 4, 16, 2, 2, 2, 128, 0>
      <<<dim3(16, 2, 16), 256, 0, stream>>>(act4, wbp, pconvo, stats5, 0);
  bn_avgpool_concat<<<16, 256, 0, stream>>>(pconvo, stats5, pg, pbb, concat, 1.f / 16384.f);

  // ---- classifier head ----
  linear_k<<<dim3(512, 16), 64, 0, stream>>>(concat, fw1, fb1, fc1o, 2112, 2112, 512, 1);
  fc_tail<<<16, 256, 0, stream>>>(fc1o, fw2, fb2, fw3, fb3, fw4, fb4, (float*)d_out);
}

// Round 7
// 408.451 us; speedup vs baseline: 1.1431x; 1.1431x over previous
//
#include <hip/hip_runtime.h>
#include <math.h>

// ---------------------------------------------------------------------------
// R7: fully chain-fused conv pipeline. Each conv (implicit-GEMM MFMA, f16,
// fp32 accum) ingests its predecessor's RAW pooled max/min planes + BN stats,
// applies BN+ReLU inline during LDS staging, and emits its own raw (pooled)
// planes + fused BN stats. conv1 is one pass (stats + pooled raw planes).
// R5 wave shapes (occupancy > per-wave intensity — R6 lesson). 14 dispatches.
// MFMA 16x16x32 f16: A m=lane&15,k=quad*8+j; B n=lane&15,k=quad*8+j;
//                    D col(n)=lane&15, row(m)=quad*4+reg.
// ---------------------------------------------------------------------------

#define PI2F 6.283185307179586f

typedef _Float16 half8 __attribute__((ext_vector_type(8)));
typedef _Float16 half4v __attribute__((ext_vector_type(4)));
typedef float f32x4 __attribute__((ext_vector_type(4)));

// ---------------- FFT branch ------------------------------------------------

__device__ __forceinline__ int bitrev8(int x) {
  x = ((x & 0x0F) << 4) | ((x >> 4) & 0x0F);
  x = ((x & 0x33) << 2) | ((x >> 2) & 0x33);
  x = ((x & 0x55) << 1) | ((x >> 1) & 0x55);
  return x;
}

__global__ __launch_bounds__(64)
void fft_rows(const float* __restrict__ x, float2* __restrict__ out) {
  __shared__ float2 s[256];
  __shared__ float2 tw[128];
  int blk = blockIdx.x;
  const float* rowp = x + (size_t)blk * 256;
  int t = threadIdx.x;
  for (int i = t; i < 128; i += 64) {
    float sn, cs;
    sincosf(-(PI2F / 256.f) * (float)i, &sn, &cs);
    tw[i] = make_float2(cs, sn);
  }
  #pragma unroll
  for (int e = 0; e < 4; ++e) {
    int i = t + (e << 6);
    s[bitrev8(i)] = make_float2(rowp[i], 0.f);
  }
  __syncthreads();
  #pragma unroll
  for (int st = 1; st <= 8; ++st) {
    int half = 1 << (st - 1);
    #pragma unroll
    for (int j = 0; j < 2; ++j) {
      int bf = t + (j << 6);
      int pos = bf & (half - 1);
      int grp = bf >> (st - 1);
      int i0 = (grp << st) | pos;
      int i1 = i0 + half;
      int k = pos << (8 - st);
      float cs = tw[k].x, sn = tw[k].y;
      float2 a = s[i0], b = s[i1];
      float tr = cs * b.x - sn * b.y;
      float ti = cs * b.y + sn * b.x;
      s[i0] = make_float2(a.x + tr, a.y + ti);
      s[i1] = make_float2(a.x - tr, a.y - ti);
    }
    __syncthreads();
  }
  float2* op = out + (size_t)blk * 256;
  #pragma unroll
  for (int e = 0; e < 4; ++e) { int i = t + (e << 6); op[i] = s[i]; }
}

__device__ __forceinline__ int radial_bin(int r2) {
  int j = (int)(sqrtf((float)r2) * 0.25f);
  while ((j + 1) * (j + 1) * 16 <= r2) ++j;
  while (j > 0 && j * j * 16 > r2) --j;
  return j;
}

__global__ __launch_bounds__(256)
void fft_cols_radial_v2(const float2* __restrict__ f, float* __restrict__ radial) {
  __shared__ float2 s[8][258];
  __shared__ float2 tw[128];
  __shared__ float bins[8][32];
  int b = blockIdx.x >> 5;
  int col0 = (blockIdx.x & 31) * 8;
  int t = threadIdx.x;
  for (int i = t; i < 128; i += 256) {
    float sn, cs;
    sincosf(-(PI2F / 256.f) * (float)i, &sn, &cs);
    tw[i] = make_float2(cs, sn);
  }
  ((float*)bins)[t] = 0.f;
  for (int idx = t; idx < 2048; idx += 256) {
    int row = idx >> 3, c = idx & 7;
    s[c][bitrev8(row)] = f[(size_t)b * 65536 + row * 256 + col0 + c];
  }
  __syncthreads();
  int c = t >> 5, l = t & 31;
  float2* sc = &s[c][0];
  #pragma unroll
  for (int st = 1; st <= 8; ++st) {
    int half = 1 << (st - 1);
    #pragma unroll
    for (int j = 0; j < 4; ++j) {
      int bf = l + (j << 5);
      int pos = bf & (half - 1);
      int grp = bf >> (st - 1);
      int i0 = (grp << st) | pos;
      int i1 = i0 + half;
      int k = pos << (8 - st);
      float cs = tw[k].x, sn = tw[k].y;
      float2 a = sc[i0], bb = sc[i1];
      float tr = cs * bb.x - sn * bb.y;
      float ti = cs * bb.y + sn * bb.x;
      sc[i0] = make_float2(a.x + tr, a.y + ti);
      sc[i1] = make_float2(a.x - tr, a.y - ti);
    }
    __syncthreads();
  }
  int dx = col0 + c - 128;
  #pragma unroll
  for (int e = 0; e < 8; ++e) {
    int i = l * 8 + e;
    float2 v = sc[i];
    float ps = v.x * v.x + v.y * v.y;
    int dy = i - 128;
    int r2 = dx * dx + dy * dy;
    if (r2 < 16384) atomicAdd(&bins[c][radial_bin(r2)], ps);
  }
  __syncthreads();
  if (t < 32) {
    float s0 = bins[0][t] + bins[1][t] + bins[2][t] + bins[3][t] +
               bins[4][t] + bins[5][t] + bins[6][t] + bins[7][t];
    atomicAdd(&radial[b * 32 + t], s0);
  }
}

__device__ __forceinline__ int isqrt_(int v) {
  int r = (int)sqrtf((float)v);
  while (r * r > v) --r;
  while ((r + 1) * (r + 1) <= v) ++r;
  return r;
}

__global__ __launch_bounds__(256)
void radial_finalize_v3(const float* __restrict__ radial, float* __restrict__ pf0) {
  __shared__ int red[4];
  __shared__ int cnt_s;
  int j = blockIdx.x, t = threadIdx.x;
  int dy = t - 128;
  int lo = 16 * j * j, hi = 16 * (j + 1) * (j + 1);
  int d2 = dy * dy;
  int cnt = 0;
  int tHi = hi - 1 - d2;
  if (tHi >= 0) {
    int rHi = isqrt_(tHi);
    int nHi = min(rHi, 127) + min(rHi, 128) + 1;
    int nLo = 0;
    int tLo = lo - 1 - d2;
    if (tLo >= 0) { int rLo = isqrt_(tLo); nLo = min(rLo, 127) + min(rLo, 128) + 1; }
    cnt = nHi - nLo;
  }
  #pragma unroll
  for (int off = 32; off > 0; off >>= 1) cnt += __shfl_down(cnt, off);
  if ((t & 63) == 0) red[t >> 6] = cnt;
  __syncthreads();
  if (t == 0) cnt_s = red[0] + red[1] + red[2] + red[3];
  __syncthreads();
  if (t < 16) {
    float cf = (float)cnt_s;
    float sum = radial[t * 32 + j];
    float val = cf > 0.f ? sum / fmaxf(cf, 1.f) : 0.f;
    pf0[t * 32 + j] = logf(val + 1e-10f);
  }
}

// ---------------- weight transforms -----------------------------------------

__global__ __launch_bounds__(256)
void wtrans_all(const float* __restrict__ cw2, const float* __restrict__ cw3,
                const float* __restrict__ cw4, const float* __restrict__ pcw,
                _Float16* __restrict__ wb2, _Float16* __restrict__ wb3,
                _Float16* __restrict__ wb4, _Float16* __restrict__ wbp) {
  int blk = blockIdx.x;
  const float* src; _Float16* dst; int COUT, CIN, KK, i;
  if (blk < 200)       { src = cw2; dst = wb2; COUT = 64;  CIN = 32;  KK = 25; i = blk * 256; }
  else if (blk < 488)  { src = cw3; dst = wb3; COUT = 128; CIN = 64;  KK = 9;  i = (blk - 200) * 256; }
  else if (blk < 1640) { src = cw4; dst = wb4; COUT = 256; CIN = 128; KK = 9;  i = (blk - 488) * 256; }
  else                 { src = pcw; dst = wbp; COUT = 128; CIN = 256; KK = 9;  i = (blk - 1640) * 256; }
  i += threadIdx.x;
  if (i >= COUT * CIN * KK) return;
  int ci = i % CIN;
  int r = i / CIN;
  int co = r % COUT;
  int tap = r / COUT;
  dst[i] = (_Float16)src[((size_t)co * CIN + ci) * KK + tap];
}

// ---------------- conv1 single pass: stats + pooled raw planes --------------

__device__ __forceinline__ void load16(float* d, const float* p) {
  f32x4 v0 = *(const f32x4*)(p);
  f32x4 v1 = *(const f32x4*)(p + 4);
  f32x4 v2 = *(const f32x4*)(p + 8);
  f32x4 v3 = *(const f32x4*)(p + 12);
  #pragma unroll
  for (int e = 0; e < 4; ++e) { d[e] = v0[e]; d[4+e] = v1[e]; d[8+e] = v2[e]; d[12+e] = v3[e]; }
}

__global__ __launch_bounds__(256)
void conv1_fused(const float* __restrict__ x, const float* __restrict__ w,
                 _Float16* __restrict__ praw, size_t minoff,
                 float* __restrict__ stats) {
  __shared__ float lds[12 * 264];
  __shared__ float r1[4][32], r2[4][32];
  int t = threadIdx.x;
  int y0 = blockIdx.x * 8, n = blockIdx.y;
  const float* xp = x + (size_t)n * 65536;
  for (int i = t; i < 12 * 264; i += 256) {
    int r = i / 264, cc = i % 264;
    int gy = y0 + r - 2, gx = cc - 4;
    lds[i] = (gy >= 0 && gy < 256 && gx >= 0 && gx < 256) ? xp[gy * 256 + gx] : 0.f;
  }
  __syncthreads();
  int c = t & 31, xg = t >> 5;
  float wreg[25];
  #pragma unroll
  for (int k = 0; k < 25; ++k) wreg[k] = w[c * 25 + k];
  float s1 = 0.f, s2 = 0.f;
  for (int strip = 0; strip < 4; ++strip) {
    int px0 = xg * 8 + strip * 64;
    float f[5][16];
    #pragma unroll
    for (int rr = 0; rr < 4; ++rr) load16(f[rr], &lds[rr * 264 + px0]);
    float pmax[4], pmin[4];
    #pragma unroll
    for (int r = 0; r < 8; ++r) {
      load16(f[(r + 4) % 5], &lds[(r + 4) * 264 + px0]);
      f32x4 A = {0.f, 0.f, 0.f, 0.f}, B = {0.f, 0.f, 0.f, 0.f};
      #pragma unroll
      for (int ky = 0; ky < 5; ++ky) {
        const float* fr = f[(r + ky) % 5];
        #pragma unroll
        for (int kx = 0; kx < 5; ++kx) {
          float wv = wreg[ky * 5 + kx];
          f32x4 ia = {fr[2 + kx], fr[3 + kx], fr[4 + kx], fr[5 + kx]};
          f32x4 ib = {fr[6 + kx], fr[7 + kx], fr[8 + kx], fr[9 + kx]};
          A += wv * ia; B += wv * ib;
        }
      }
      s1 += A[0] + A[1] + A[2] + A[3] + B[0] + B[1] + B[2] + B[3];
      s2 += A[0]*A[0] + A[1]*A[1] + A[2]*A[2] + A[3]*A[3]
          + B[0]*B[0] + B[1]*B[1] + B[2]*B[2] + B[3]*B[3];
      float cm[4], cn[4];
      cm[0] = fmaxf(A[0], A[1]); cn[0] = fminf(A[0], A[1]);
      cm[1] = fmaxf(A[2], A[3]); cn[1] = fminf(A[2], A[3]);
      cm[2] = fmaxf(B[0], B[1]); cn[2] = fminf(B[0], B[1]);
      cm[3] = fmaxf(B[2], B[3]); cn[3] = fminf(B[2], B[3]);
      if ((r & 1) == 0) {
        #pragma unroll
        for (int k = 0; k < 4; ++k) { pmax[k] = cm[k]; pmin[k] = cn[k]; }
      } else {
        int prow = (y0 + r) >> 1;
        int pc0 = px0 >> 1;
        #pragma unroll
        for (int k = 0; k < 4; ++k) {
          size_t idx = (((size_t)n * 128 + prow) * 128 + pc0 + k) * 32 + c;
          praw[idx] = (_Float16)fmaxf(pmax[k], cm[k]);
          praw[minoff + idx] = (_Float16)fminf(pmin[k], cn[k]);
        }
      }
    }
  }
  s1 += __shfl_down(s1, 32);
  s2 += __shfl_down(s2, 32);
  if ((t & 63) < 32) { r1[t >> 6][t & 31] = s1; r2[t >> 6][t & 31] = s2; }
  __syncthreads();
  if (t < 32) {
    float* st = stats + (blockIdx.x & 7) * 64;
    atomicAdd(&st[t],      r1[0][t] + r1[1][t] + r1[2][t] + r1[3][t]);
    atomicAdd(&st[32 + t], r2[0][t] + r2[1][t] + r2[2][t] + r2[3][t]);
  }
}

// ---------------- chain-fused implicit-GEMM MFMA conv -----------------------
// Staging applies predecessor BN (from 8-slice stats) + ReLU inline; INPOOL
// selects max/min plane by sign of scale (exact pool-before-affine identity).
// Epilogue: OUTPOOL -> pooled raw max/min planes, else full-res raw; fused
// fp32 BN stats -> 8 atomic slices.

template <int CIN, int COUT, int H, int W, int K, int TH, int TW, int CW,
          int COT, int PT, int SLAB, int INPOOL, int OUTPOOL>
__global__ __launch_bounds__(256)
void conv_mfma4(const _Float16* __restrict__ in, size_t in_minoff,
                const _Float16* __restrict__ wb,
                _Float16* __restrict__ out, size_t out_minoff,
                const float* __restrict__ instats, const float* __restrict__ ing,
                const float* __restrict__ inbb, float in_invN,
                float* __restrict__ stats) {
  constexpr int P = K / 2, R = TH + 2 * P, XW = TW + 2 * P, PIX = R * XW;
  constexpr int TAPS = K * K, CSP = SLAB + 8;
  constexpr int NCC = SLAB / 32, NPH = CIN / SLAB, SUBS = SLAB / 8;
  constexpr int PW = 4 / CW, COB = CW * 16 * COT;
  static_assert(TH * TW == PW * 16 * PT, "pos tile mismatch");
  static_assert(TW == 16, "row-per-fragment requires TW=16");
  static_assert(!OUTPOOL || (PT % 2 == 0), "pool needs even PT");
  __shared__ _Float16 lds[PIX * CSP];
  __shared__ float inscs[CIN], inshs[CIN];
  __shared__ float sst[2][COB];
  int t = threadIdx.x;
  int lane = t & 63, wv = t >> 6;
  int lane15 = lane & 15, quad = lane >> 4;
  constexpr int WT = W / TW;
  int x0 = (blockIdx.x % WT) * TW, y0 = (blockIdx.x / WT) * TH;
  int coB = blockIdx.y * COB;
  int nb = blockIdx.z;
  int co_off = (wv % CW) * (16 * COT);
  int rowbase = (wv / CW) * PT;

  for (int i = t; i < 2 * COB; i += 256) ((float*)sst)[i] = 0.f;
  for (int c = t; c < CIN; c += 256) {
    float s1 = 0.f, s2 = 0.f;
    #pragma unroll
    for (int s = 0; s < 8; ++s) {
      s1 += instats[s * 2 * CIN + c];
      s2 += instats[s * 2 * CIN + CIN + c];
    }
    float mean = s1 * in_invN;
    float var  = s2 * in_invN - mean * mean;
    float k = ing[c] / sqrtf(var + 1e-5f);
    inscs[c] = k; inshs[c] = inbb[c] - mean * k;
  }
  __syncthreads();

  f32x4 acc[COT][PT];
  #pragma unroll
  for (int ct = 0; ct < COT; ++ct)
    #pragma unroll
    for (int pt = 0; pt < PT; ++pt)
      #pragma unroll
      for (int e = 0; e < 4; ++e) acc[ct][pt][e] = 0.f;

  int bbase[PT];
  #pragma unroll
  for (int pt = 0; pt < PT; ++pt)
    bbase[pt] = ((rowbase + pt) * XW + lane15) * CSP + quad * 8;
  const _Float16* aptr[COT];
  #pragma unroll
  for (int ct = 0; ct < COT; ++ct)
    aptr[ct] = wb + (size_t)(coB + co_off + ct * 16 + lane15) * CIN + quad * 8;

  const size_t ibase = (size_t)nb * H * W * CIN;

  #pragma unroll
  for (int ph = 0; ph < NPH; ++ph) {
    constexpr int ITEMS = PIX * SUBS;
    for (int i = t; i < ITEMS; i += 256) {
      int sub = i % SUBS, pix = i / SUBS;
      int r = pix / XW, xx = pix % XW;
      int gy = y0 + r - P, gx = x0 + xx - P;
      int ch = ph * SLAB + sub * 8;
      half8 v;
      #pragma unroll
      for (int j = 0; j < 8; ++j) v[j] = (_Float16)0.f;
      if (gy >= 0 && gy < H && gx >= 0 && gx < W) {
        size_t off = ibase + ((size_t)gy * W + gx) * CIN + ch;
        half8 vmx = *(const half8*)(in + off);
        if (INPOOL) {
          half8 vmn = *(const half8*)(in + in_minoff + off);
          #pragma unroll
          for (int j = 0; j < 8; ++j) {
            float sc = inscs[ch + j];
            float xv = sc >= 0.f ? (float)vmx[j] : (float)vmn[j];
            v[j] = (_Float16)fmaxf(sc * xv + inshs[ch + j], 0.f);
          }
        } else {
          #pragma unroll
          for (int j = 0; j < 8; ++j) {
            float sc = inscs[ch + j];
            v[j] = (_Float16)fmaxf(sc * (float)vmx[j] + inshs[ch + j], 0.f);
          }
        }
      }
      *(half8*)(&lds[pix * CSP + sub * 8]) = v;
    }
    __syncthreads();
    #pragma unroll
    for (int cc = 0; cc < NCC; ++cc) {
      #pragma unroll
      for (int tap = 0; tap < TAPS; ++tap) {
        int ky = tap / K, kx = tap % K;
        half8 a[COT], b[PT];
        #pragma unroll
        for (int ct = 0; ct < COT; ++ct)
          a[ct] = *(const half8*)(aptr[ct] + (size_t)tap * COUT * CIN +
                                  ph * SLAB + cc * 32);
        #pragma unroll
        for (int pt = 0; pt < PT; ++pt)
          b[pt] = *(const half8*)(&lds[bbase[pt] + (ky * XW + kx) * CSP + cc * 32]);
        #pragma unroll
        for (int ct = 0; ct < COT; ++ct)
          #pragma unroll
          for (int pt = 0; pt < PT; ++pt)
            acc[ct][pt] = __builtin_amdgcn_mfma_f32_16x16x32_f16(
                a[ct], b[pt], acc[ct][pt], 0, 0, 0);
      }
    }
    if (ph + 1 < NPH) __syncthreads();
  }

  if (OUTPOOL) {
    #pragma unroll
    for (int ct = 0; ct < COT; ++ct)
      #pragma unroll
      for (int pp = 0; pp < PT; pp += 2) {
        half4v hmax, hmin;
        #pragma unroll
        for (int e = 0; e < 4; ++e) {
          float vmx = fmaxf(acc[ct][pp][e], acc[ct][pp + 1][e]);
          float vmn = fminf(acc[ct][pp][e], acc[ct][pp + 1][e]);
          float omx = fmaxf(vmx, __shfl_xor(vmx, 1));
          float omn = fminf(vmn, __shfl_xor(vmn, 1));
          hmax[e] = (_Float16)omx; hmin[e] = (_Float16)omn;
        }
        if ((lane15 & 1) == 0) {
          int co = coB + co_off + ct * 16 + quad * 4;
          int prow = (y0 + rowbase + pp) >> 1;
          int pcol = (x0 >> 1) + (lane15 >> 1);
          size_t idx = (((size_t)nb * (H / 2) + prow) * (W / 2) + pcol) * COUT + co;
          *(half4v*)(out + idx) = hmax;
          *(half4v*)(out + out_minoff + idx) = hmin;
        }
      }
  } else {
    #pragma unroll
    for (int ct = 0; ct < COT; ++ct)
      #pragma unroll
      for (int pt = 0; pt < PT; ++pt) {
        int co = coB + co_off + ct * 16 + quad * 4;
        int y = y0 + rowbase + pt, x = x0 + lane15;
        _Float16* op = out + (((size_t)nb * H + y) * W + x) * COUT + co;
        half4v h;
        #pragma unroll
        for (int e = 0; e < 4; ++e) h[e] = (_Float16)acc[ct][pt][e];
        *(half4v*)op = h;
      }
  }

  #pragma unroll
  for (int ct = 0; ct < COT; ++ct)
    #pragma unroll
    for (int e = 0; e < 4; ++e) {
      float sv = 0.f, sq = 0.f;
      #pragma unroll
      for (int pt = 0; pt < PT; ++pt) {
        float v = acc[ct][pt][e];
        sv += v; sq += v * v;
      }
      sv += __shfl_xor(sv, 1); sq += __shfl_xor(sq, 1);
      sv += __shfl_xor(sv, 2); sq += __shfl_xor(sq, 2);
      sv += __shfl_xor(sv, 4); sq += __shfl_xor(sq, 4);
      sv += __shfl_xor(sv, 8); sq += __shfl_xor(sq, 8);
      if (lane15 == 0) {
        int cl = co_off + ct * 16 + quad * 4 + e;
        atomicAdd(&sst[0][cl], sv);
        atomicAdd(&sst[1][cl], sq);
      }
    }
  __syncthreads();
  float* st = stats + (blockIdx.x & 7) * 2 * COUT;
  for (int i = t; i < COB; i += 256) {
    atomicAdd(&st[coB + i], sst[0][i]);
    atomicAdd(&st[COUT + coB + i], sst[1][i]);
  }
}

// ---------------- pconv epilogue: BN + ReLU + 8x8 avgpool -> concat ---------

__global__ __launch_bounds__(256)
void bn_avgpool_concat(const _Float16* __restrict__ x, const float* __restrict__ stats,
                       const float* __restrict__ g, const float* __restrict__ bb,
                       float* __restrict__ concat, float invN) {
  __shared__ float scs[128], shs[128];
  int t = threadIdx.x;
  int n = blockIdx.y;
  for (int c = t; c < 128; c += 256) {
    float s1 = 0.f, s2 = 0.f;
    #pragma unroll
    for (int s = 0; s < 8; ++s) {
      s1 += stats[s * 256 + c];
      s2 += stats[s * 256 + 128 + c];
    }
    float mean = s1 * invN;
    float var  = s2 * invN - mean * mean;
    float k = g[c] / sqrtf(var + 1e-5f);
    scs[c] = k; shs[c] = bb[c] - mean * k;
  }
  __syncthreads();
  int i = blockIdx.x * 256 + t;   // 0..2047
  int c = i & 127, opix = i >> 7;
  int py = opix >> 2, px = opix & 3;
  float sc = scs[c], sh = shs[c];
  float s = 0.f;
  for (int yy = 0; yy < 8; ++yy)
    #pragma unroll
    for (int xx = 0; xx < 8; ++xx)
      s += fmaxf((float)x[(((size_t)n * 32 + py * 8 + yy) * 32 + px * 8 + xx) * 128 + c] * sc + sh, 0.f);
  concat[(size_t)n * 2112 + c * 16 + opix] = s * (1.f / 64.f);
}

// ---------------- MLP heads -------------------------------------------------

__global__ __launch_bounds__(64)
void linear_k(const float* __restrict__ in, const float* __restrict__ w,
              const float* __restrict__ bias, float* __restrict__ out,
              int I, int in_stride, int out_stride, int relu) {
  int o = blockIdx.x, b = blockIdx.y;
  int lane = threadIdx.x;
  const float* ip = in + (size_t)b * in_stride;
  const float* wp = w + (size_t)o * I;
  float acc = 0.f;
  for (int i = lane; i < I; i += 64) acc += ip[i] * wp[i];
  #pragma unroll
  for (int off = 32; off > 0; off >>= 1) acc += __shfl_down(acc, off);
  if (lane == 0) {
    float v = acc + bias[o];
    if (relu) v = fmaxf(v, 0.f);
    out[(size_t)b * out_stride + o] = v;
  }
}

__global__ __launch_bounds__(256)
void pf_mlp(const float* __restrict__ pf0,
            const float* __restrict__ pw1, const float* __restrict__ pb1,
            const float* __restrict__ pw2, const float* __restrict__ pb2,
            const float* __restrict__ pw3, const float* __restrict__ pb3,
            float* __restrict__ concat) {
  __shared__ float a0[32], a1[256], a2[128];
  int b = blockIdx.x, t = threadIdx.x;
  if (t < 32) a0[t] = pf0[b * 32 + t];
  __syncthreads();
  {
    float s = pb1[t];
    for (int i = 0; i < 32; ++i) s += pw1[t * 32 + i] * a0[i];
    a1[t] = fmaxf(s, 0.f);
  }
  __syncthreads();
  if (t < 128) {
    float s = pb2[t];
    for (int i = 0; i < 256; ++i) s += pw2[t * 256 + i] * a1[i];
    a2[t] = fmaxf(s, 0.f);
  }
  __syncthreads();
  if (t < 64) {
    float s = pb3[t];
    for (int i = 0; i < 128; ++i) s += pw3[t * 128 + i] * a2[i];
    concat[(size_t)b * 2112 + 2048 + t] = fmaxf(s, 0.f);
  }
}

__global__ __launch_bounds__(256)
void fc_tail(const float* __restrict__ fc1o,
             const float* __restrict__ fw2, const float* __restrict__ fb2,
             const float* __restrict__ fw3, const float* __restrict__ fb3,
             const float* __restrict__ fw4, const float* __restrict__ fb4,
             float* __restrict__ out) {
  __shared__ float a1[512], a2[256], a3[128];
  int b = blockIdx.x, t = threadIdx.x;
  a1[t] = fc1o[b * 512 + t];
  a1[t + 256] = fc1o[b * 512 + t + 256];
  __syncthreads();
  {
    float s = fb2[t];
    for (int i = 0; i < 512; ++i) s += fw2[t * 512 + i] * a1[i];
    a2[t] = fmaxf(s, 0.f);
  }
  __syncthreads();
  if (t < 128) {
    float s = fb3[t];
    for (int i = 0; i < 256; ++i) s += fw3[t * 256 + i] * a2[i];
    a3[t] = fmaxf(s, 0.f);
  }
  __syncthreads();
  if (t < 2) {
    float s = fb4[t];
    for (int i = 0; i < 128; ++i) s += fw4[t * 128 + i] * a3[i];
    out[b * 2 + t] = s;
  }
}

// ---------------------------------------------------------------------------

extern "C" void kernel_launch(void* const* d_in, const int* in_sizes, int n_in,
                              void* d_out, int out_size, void* d_ws, size_t ws_size,
                              hipStream_t stream) {
  (void)in_sizes; (void)n_in; (void)out_size; (void)ws_size;
  const float* x   = (const float*)d_in[0];
  const float* cw1 = (const float*)d_in[1];
  const float* g1  = (const float*)d_in[3];
  const float* bb1 = (const float*)d_in[4];
  const float* cw2 = (const float*)d_in[5];
  const float* g2  = (const float*)d_in[7];
  const float* bb2 = (const float*)d_in[8];
  const float* cw3 = (const float*)d_in[9];
  const float* g3  = (const float*)d_in[11];
  const float* bb3 = (const float*)d_in[12];
  const float* cw4 = (const float*)d_in[13];
  const float* g4  = (const float*)d_in[15];
  const float* bb4 = (const float*)d_in[16];
  const float* pcw = (const float*)d_in[17];
  const float* pg  = (const float*)d_in[19];
  const float* pbb = (const float*)d_in[20];
  const float* pw1 = (const float*)d_in[21];
  const float* pb1 = (const float*)d_in[22];
  const float* pw2 = (const float*)d_in[23];
  const float* pb2 = (const float*)d_in[24];
  const float* pw3 = (const float*)d_in[25];
  const float* pb3 = (const float*)d_in[26];
  const float* fw1 = (const float*)d_in[27];
  const float* fb1 = (const float*)d_in[28];
  const float* fw2 = (const float*)d_in[29];
  const float* fb2 = (const float*)d_in[30];
  const float* fw3 = (const float*)d_in[31];
  const float* fb3 = (const float*)d_in[32];
  const float* fw4 = (const float*)d_in[33];
  const float* fb4 = (const float*)d_in[34];

  char* base = (char*)d_ws;
  // Region A (33.5 MB): pool1raw max/min -> pool3raw max/min + pconvo
  _Float16* pool1raw = (_Float16*)(base + 0);           // 2x [16,128,128,32]
  _Float16* pool3raw = (_Float16*)(base + 0);           // 2x [16,32,32,128]
  _Float16* pconvo   = (_Float16*)(base + 8388608);     // [16,32,32,128]
  // Region B (16.8 MB): fftbuf -> pool2raw max/min -> conv4raw
  _Float16* pool2raw = (_Float16*)(base + 33554432);    // 2x [16,64,64,64]
  float2*   fftbuf   = (float2*)(base + 33554432);
  _Float16* conv4raw = (_Float16*)(base + 33554432);    // [16,32,32,256]
  _Float16* wb2      = (_Float16*)(base + 50331648);
  _Float16* wb3      = (_Float16*)(base + 50434048);
  _Float16* wb4      = (_Float16*)(base + 50581504);
  _Float16* wbp      = (_Float16*)(base + 51171328);
  float*    zbase    = (float*)(base + 51761152);       // 10240 floats
  float*    stats1   = zbase;               // 8*64
  float*    stats2   = zbase + 512;         // 8*128
  float*    stats3   = zbase + 1536;        // 8*256
  float*    stats4   = zbase + 3584;        // 8*512
  float*    stats5   = zbase + 7680;        // 8*256
  float*    radial   = zbase + 9728;        // 512
  float*    pf0      = (float*)(base + 51802112);
  float*    concat   = (float*)(base + 51804160);       // 16*2112
  float*    fc1o     = (float*)(base + 51939328);

  hipMemsetAsync(zbase, 0, 10240 * sizeof(float), stream);

  wtrans_all<<<2792, 256, 0, stream>>>(cw2, cw3, cw4, pcw, wb2, wb3, wb4, wbp);

  // ---- FFT / power-features branch (fftbuf aliases region B) ----
  fft_rows<<<4096, 64, 0, stream>>>(x, fftbuf);
  fft_cols_radial_v2<<<512, 256, 0, stream>>>(fftbuf, radial);
  radial_finalize_v3<<<32, 256, 0, stream>>>(radial, pf0);
  pf_mlp<<<16, 256, 0, stream>>>(pf0, pw1, pb1, pw2, pb2, pw3, pb3, concat);

  // ---- conv1: one pass -> pooled raw planes + stats ----
  conv1_fused<<<dim3(32, 16), 256, 0, stream>>>(x, cw1, pool1raw, 8388608, stats1);

  // ---- conv2: in=pool1raw(sel via stats1), out=pool2raw pooled planes ----
  conv_mfma4<32, 64, 128, 128, 5, 8, 16, 2, 2, 4, 32, 1, 1>
      <<<dim3(128, 1, 16), 256, 0, stream>>>(
      pool1raw, 8388608, wb2, pool2raw, 4194304,
      stats1, g1, bb1, 1.f / 1048576.f, stats2);

  // ---- conv3: in=pool2raw(stats2), out=pool3raw pooled planes ----
  conv_mfma4<64, 128, 64, 64, 3, 8, 16, 2, 4, 4, 64, 1, 1>
      <<<dim3(32, 1, 16), 256, 0, stream>>>(
      pool2raw, 4194304, wb3, pool3raw, 2097152,
      stats2, g2, bb2, 1.f / 262144.f, stats3);

  // ---- conv4: in=pool3raw(stats3), out=conv4raw full-res ----
  conv_mfma4<128, 256, 32, 32, 3, 4, 16, 2, 2, 2, 128, 1, 0>
      <<<dim3(16, 4, 16), 256, 0, stream>>>(
      pool3raw, 2097152, wb4, conv4raw, 0,
      stats3, g3, bb3, 1.f / 65536.f, stats4);

  // ---- pconv: in=conv4raw(stats4, plain), out=pconvo raw ----
  conv_mfma4<256, 128, 32, 32, 3, 4, 16, 2, 2, 2, 128, 0, 0>
      <<<dim3(16, 2, 16), 256, 0, stream>>>(
      conv4raw, 0, wbp, pconvo, 0,
      stats4, g4, bb4, 1.f / 16384.f, stats5);
  bn_avgpool_concat<<<dim3(8, 16), 256, 0, stream>>>(
      pconvo, stats5, pg, pbb, concat, 1.f / 16384.f);

  // ---- classifier head ----
  linear_k<<<dim3(512, 16), 64, 0, stream>>>(concat, fw1, fb1, fc1o, 2112, 2112, 512, 1);
  fc_tail<<<16, 256, 0, stream>>>(fc1o, fw2, fb2, fw3, fb3, fw4, fb4, (float*)d_out);
}